// Round 4
// baseline (628.784 us; speedup 1.0000x reference)
//
#include <hip/hip_runtime.h>
#include <stdint.h>

// ---------------------------------------------------------------------------
// MHSA: B=8, N=1024, C=768, H=12, HD=64, SCALE=0.125
// Inputs/outputs fp32; internal compute bf16 MFMA with fp32 accumulation.
// Round 15: ONE persistent mega-kernel (768 blocks = 256 CU x 3, exactly
// co-resident: LDS 48KB -> 3 blocks/CU, __launch_bounds__(256,3) caps VGPR).
// Phases: prep(7/block) -> bar -> qkv gemm(3 tiles/block) -> bar -> attn
// (1 tile/block) -> bar -> out gemm(1 tile/block). Manual agent-scope atomic
// grid barriers (counters memset-reset per graph replay). Eliminates 3
// launch gaps (~11.5us each, measured R2->R3). XCD swizzle REVERTED
// (measured regression: FETCH 72.6->45.7MB as predicted but dur 63->73us —
// kernel is not fetch-limited; chunked mapping hot-spots L2 channels).
// ---------------------------------------------------------------------------

typedef __attribute__((ext_vector_type(8))) __bf16 bf16x8;
typedef __attribute__((ext_vector_type(4))) float f32x4;

__device__ __forceinline__ uint16_t f2bf(float f) {
    union { float f; unsigned u; } c; c.f = f;
    unsigned x = c.u;
    unsigned r = (x + 0x7FFFu + ((x >> 16) & 1u)) >> 16;  // round-nearest-even
    return (uint16_t)r;
}

__device__ __forceinline__ void gload_lds16(const uint16_t* g, uint16_t* l) {
    __builtin_amdgcn_global_load_lds(
        (const __attribute__((address_space(1))) unsigned int*)g,
        (__attribute__((address_space(3))) unsigned int*)l, 16, 0, 0);
}

// Grid-wide barrier: all 768 blocks are co-resident by construction.
// Release: per-thread fence (drains stores, L2 writeback) + block barrier,
// then thread 0 atomics at agent scope; acquire on the spin load invalidates
// stale cache lines before the post-barrier block proceeds.
__device__ __forceinline__ void grid_barrier(unsigned* bar) {
    __threadfence();
    __syncthreads();
    if (threadIdx.x == 0) {
        __hip_atomic_fetch_add(bar, 1u, __ATOMIC_RELEASE, __HIP_MEMORY_SCOPE_AGENT);
        while (__hip_atomic_load(bar, __ATOMIC_RELAXED, __HIP_MEMORY_SCOPE_AGENT) < 768u)
            __builtin_amdgcn_s_sleep(16);
        (void)__hip_atomic_load(bar, __ATOMIC_ACQUIRE, __HIP_MEMORY_SCOPE_AGENT);
    }
    __syncthreads();
}

// Shared-memory overlay for all phases (48 KB).
union SMem {
    struct { uint16_t lA[2 * 2 * 2048]; uint16_t lB[2 * 2 * 4096]; } g;  // gemm
    uint16_t P[4 * 2 * 16 * 40];                                         // attn
    uint16_t tile[32][33];                                               // prep
};

// ---------------------------------------------------------------------------
// Prep unit: bid<3072 convert x fp32->bf16 (2048 elem/block);
// [3072,4800) transpose w_qkv [768][2304] -> [2304][768];
// [4800,5376) transpose w_out [768][768] -> [768][768].
// ---------------------------------------------------------------------------
__device__ __forceinline__ void prep_unit(
    int bid, int tid, const float* __restrict__ x, uint16_t* __restrict__ xbf,
    const float* __restrict__ w_qkv, uint16_t* __restrict__ wtqkv,
    const float* __restrict__ w_out, uint16_t* __restrict__ wtout,
    uint16_t (*tile)[33]) {
    if (bid < 3072) {
        int i = (bid * 256 + tid) * 8;
        float4 a = *(const float4*)(x + i);
        float4 b = *(const float4*)(x + i + 4);
        union { uint16_t u[8]; uint4 v; } o;
        o.u[0] = f2bf(a.x); o.u[1] = f2bf(a.y); o.u[2] = f2bf(a.z); o.u[3] = f2bf(a.w);
        o.u[4] = f2bf(b.x); o.u[5] = f2bf(b.y); o.u[6] = f2bf(b.z); o.u[7] = f2bf(b.w);
        *(uint4*)(xbf + i) = o.v;
    } else {
        const float* src; uint16_t* dst; int Cc, bx, by;
        if (bid < 4800) {
            int id = bid - 3072;
            src = w_qkv; dst = wtqkv; Cc = 2304;
            bx = id % 72; by = id / 72;
        } else {
            int id = bid - 4800;
            src = w_out; dst = wtout; Cc = 768;
            bx = id % 24; by = id / 24;
        }
        const int R = 768;
        int tx = tid & 31, ty = tid >> 5;
        int c0 = bx * 32, r0 = by * 32;
#pragma unroll
        for (int i = 0; i < 4; i++) {
            int r = ty + i * 8;
            tile[r][tx] = f2bf(src[(size_t)(r0 + r) * Cc + c0 + tx]);
        }
        __syncthreads();
#pragma unroll
        for (int i = 0; i < 4; i++) {
            int r = ty + i * 8;
            dst[(size_t)(c0 + r) * R + r0 + tx] = tile[tx][r];
        }
        __syncthreads();  // protect tile reuse on the next virtual block
    }
}

// ---------------------------------------------------------------------------
// GEMM 64x128 tile, BK=64 (two 32-k sub-tiles per barrier), LDS dbuf,
// XOR-swizzled staging (conflict-free frag reads). Plain x-major tile map.
// MODE 0: QKV epilogue (q pre-scaled 0.125*log2e; k,v fragment-scatter).
// MODE 1: bias + fp32 out.
// ---------------------------------------------------------------------------
template <int MODE>
__device__ __forceinline__ void gemm_tile(
    int bx, int by, const uint16_t* __restrict__ A, const uint16_t* __restrict__ Bt,
    int Kdim, int Ncols, uint16_t* lA, uint16_t* lB,
    uint16_t* __restrict__ qws, uint16_t* __restrict__ kws,
    uint16_t* __restrict__ vtws,
    const float* __restrict__ bias, float* __restrict__ outp) {
    int tid = threadIdx.x;
    int w = tid >> 6, lane = tid & 63, quad = lane >> 4, lo = lane & 15;
    int mw = w >> 1, nw = w & 1;
    int m0 = by * 64, n0 = bx * 128;

    int srow = tid >> 2;
    int skc = ((tid & 3) ^ ((tid >> 3) & 3)) * 8;
    const uint16_t* gA0 = A + (size_t)(m0 + srow) * Kdim + skc;
    const uint16_t* gB0 = Bt + (size_t)(n0 + srow) * Kdim + skc;
    const uint16_t* gB1 = gB0 + (size_t)64 * Kdim;

    f32x4 acc[2][4];
#pragma unroll
    for (int i = 0; i < 2; i++)
#pragma unroll
        for (int j = 0; j < 4; j++) acc[i][j] = (f32x4){0.f, 0.f, 0.f, 0.f};

    int swz = (quad ^ ((lo >> 1) & 3)) * 8;
    int aoff = (mw * 32 + lo) * 32 + swz;
    int boff = (nw * 64 + lo) * 32 + swz;

    const int nIter = Kdim >> 6;  // BK=64

#pragma unroll
    for (int s = 0; s < 2; s++) {
        gload_lds16(gA0 + s * 32, lA + s * 2048 + tid * 8);
        gload_lds16(gB0 + s * 32, lB + s * 4096 + tid * 8);
        gload_lds16(gB1 + s * 32, lB + s * 4096 + 2048 + tid * 8);
    }
    __syncthreads();

    for (int it = 0; it < nIter; it++) {
        const int cur = it & 1, nxt = cur ^ 1;
        const int kn = (it + 1 < nIter) ? (it + 1) * 64 : 0;  // last redundant

#pragma unroll
        for (int s = 0; s < 2; s++) {
            gload_lds16(gA0 + kn + s * 32, lA + (nxt * 2 + s) * 2048 + tid * 8);
            gload_lds16(gB0 + kn + s * 32, lB + (nxt * 2 + s) * 4096 + tid * 8);
            gload_lds16(gB1 + kn + s * 32, lB + (nxt * 2 + s) * 4096 + 2048 + tid * 8);
        }

#pragma unroll
        for (int s = 0; s < 2; s++) {
            bf16x8 af[2], bfr[4];
#pragma unroll
            for (int i = 0; i < 2; i++)
                af[i] = *(const bf16x8*)(lA + (cur * 2 + s) * 2048 + aoff + i * 512);
#pragma unroll
            for (int j = 0; j < 4; j++)
                bfr[j] = *(const bf16x8*)(lB + (cur * 2 + s) * 4096 + boff + j * 512);
#pragma unroll
            for (int i = 0; i < 2; i++)
#pragma unroll
                for (int j = 0; j < 4; j++)
                    acc[i][j] = __builtin_amdgcn_mfma_f32_16x16x32_bf16(
                        af[i], bfr[j], acc[i][j], 0, 0, 0);
        }
        __syncthreads();  // drains prefetch (hidden by 16 MFMAs) + WAR on cur
    }

    if (MODE == 0) {
        int part = n0 / 768;
        int ccb = n0 % 768 + nw * 64;
        float qsc = (part == 0) ? 0.18033688011112042f : 1.0f;  // 0.125*log2(e)
#pragma unroll
        for (int i = 0; i < 2; i++)
#pragma unroll
            for (int j = 0; j < 4; j++)
#pragma unroll
                for (int r = 0; r < 4; r++) {
                    int m = m0 + mw * 32 + i * 16 + quad * 4 + r;
                    int bidx = m >> 10, nidx = m & 1023;
                    int cc = ccb + j * 16 + lo;
                    int h = cc >> 6, d = cc & 63;
                    int bh = bidx * 12 + h;
                    uint16_t v = f2bf(acc[i][j][r] * qsc);
                    int kt = nidx >> 5, keyin = nidx & 31;
                    if (part == 0) {
                        qws[((size_t)bh * 1024 + nidx) * 64 + d] = v;
                    } else if (part == 1) {
                        int fs = ((d >> 5) << 1) | (keyin & 1);
                        int idx = ((bh << 5) + kt) * 2048 + fs * 512 +
                                  ((((d & 31) >> 3) << 4) + (keyin >> 1)) * 8 + (d & 7);
                        kws[idx] = v;
                    } else {
                        int idx = ((bh << 5) + kt) * 2048 + (d >> 4) * 512 +
                                  (((keyin >> 3) << 4) + (d & 15)) * 8 + (keyin & 7);
                        vtws[idx] = v;
                    }
                }
    } else {
#pragma unroll
        for (int i = 0; i < 2; i++)
#pragma unroll
            for (int j = 0; j < 4; j++)
#pragma unroll
                for (int r = 0; r < 4; r++) {
                    int m = m0 + mw * 32 + i * 16 + quad * 4 + r;
                    int c = n0 + nw * 64 + j * 16 + lo;
                    outp[(size_t)m * Ncols + c] = acc[i][j][r] + bias[c];
                }
    }
}

// ---------------------------------------------------------------------------
// Flash attention tile: no K/V LDS staging (K/V L2-resident, fragment-order
// coalesced global reads); per-wave P staging; barrier-free.
// ---------------------------------------------------------------------------
__device__ __forceinline__ void attn_tile(
    int bh, int qt, const uint16_t* __restrict__ qws,
    const uint16_t* __restrict__ kws, const uint16_t* __restrict__ vtws,
    uint16_t* __restrict__ attnout, uint16_t* Pb) {
    int tid = threadIdx.x;
    int w = tid >> 6, lane = tid & 63, quad = lane >> 4, lo = lane & 15;
    int q0 = qt * 128 + w * 32;

    const uint16_t* Qb = qws + (size_t)bh * 65536;
    const uint16_t* Kt = kws + (size_t)bh * 65536;   // 32 tiles x 2048 u16
    const uint16_t* Vt = vtws + (size_t)bh * 65536;

    bf16x8 aq[2][2];
#pragma unroll
    for (int rg = 0; rg < 2; rg++)
#pragma unroll
        for (int h = 0; h < 2; h++)
            aq[rg][h] = *(const bf16x8*)(Qb + (size_t)(q0 + rg * 16 + lo) * 64 + h * 32 + quad * 8);

    f32x4 oacc[2][4], ol[2];
#pragma unroll
    for (int rg = 0; rg < 2; rg++) {
        ol[rg] = (f32x4){0.f, 0.f, 0.f, 0.f};
#pragma unroll
        for (int nd = 0; nd < 4; nd++) oacc[rg][nd] = (f32x4){0.f, 0.f, 0.f, 0.f};
    }

    bf16x8 ones;
#pragma unroll
    for (int i = 0; i < 8; i++) ones[i] = (__bf16)1.0f;

    const f32x4 zero4 = (f32x4){0.f, 0.f, 0.f, 0.f};

#pragma unroll 2
    for (int kt = 0; kt < 32; kt++) {
        const uint16_t* Kb = Kt + kt * 2048;
        const uint16_t* Vb = Vt + kt * 2048;

        bf16x8 bk[2][2], vv[4];
#pragma unroll
        for (int t = 0; t < 2; t++)
#pragma unroll
            for (int h = 0; h < 2; h++)
                bk[t][h] = *(const bf16x8*)(Kb + (h * 2 + t) * 512 + lane * 8);
#pragma unroll
        for (int nd = 0; nd < 4; nd++)
            vv[nd] = *(const bf16x8*)(Vb + nd * 512 + lane * 8);

#pragma unroll
        for (int rg = 0; rg < 2; rg++) {
            f32x4 s0 = __builtin_amdgcn_mfma_f32_16x16x32_bf16(aq[rg][0], bk[0][0], zero4, 0, 0, 0);
            s0 = __builtin_amdgcn_mfma_f32_16x16x32_bf16(aq[rg][1], bk[0][1], s0, 0, 0, 0);
            f32x4 s1 = __builtin_amdgcn_mfma_f32_16x16x32_bf16(aq[rg][0], bk[1][0], zero4, 0, 0, 0);
            s1 = __builtin_amdgcn_mfma_f32_16x16x32_bf16(aq[rg][1], bk[1][1], s1, 0, 0, 0);
#pragma unroll
            for (int r = 0; r < 4; r++) {
                union { float f; unsigned u; } u0, u1;
                u0.f = __builtin_exp2f(s0[r]);  // key 2*lo
                u1.f = __builtin_exp2f(s1[r]);  // key 2*lo+1
                unsigned pk = __builtin_amdgcn_perm(u1.u, u0.u, 0x07060302u);
                *(unsigned*)(Pb + ((w * 2 + rg) * 16 + quad * 4 + r) * 40 + 2 * lo) = pk;
            }
        }

#pragma unroll
        for (int rg = 0; rg < 2; rg++) {
            bf16x8 ap = *(const bf16x8*)(Pb + ((w * 2 + rg) * 16 + lo) * 40 + quad * 8);
            ol[rg] = __builtin_amdgcn_mfma_f32_16x16x32_bf16(ap, ones, ol[rg], 0, 0, 0);
#pragma unroll
            for (int nd = 0; nd < 4; nd++)
                oacc[rg][nd] = __builtin_amdgcn_mfma_f32_16x16x32_bf16(ap, vv[nd], oacc[rg][nd], 0, 0, 0);
        }
    }

    int b = bh / 12, hh = bh % 12;
#pragma unroll
    for (int rg = 0; rg < 2; rg++)
#pragma unroll
        for (int r = 0; r < 4; r++) {
            float inv = 1.0f / ol[rg][r];
            int n = q0 + rg * 16 + quad * 4 + r;
            size_t base = ((size_t)(b * 1024 + n)) * 768 + hh * 64;
#pragma unroll
            for (int nd = 0; nd < 4; nd++)
                attnout[base + nd * 16 + lo] = f2bf(oacc[rg][nd][r] * inv);
        }
}

// ---------------------------------------------------------------------------
// Persistent mega-kernel: 768 blocks x 256 threads, all phases.
// 768 = 256 CU x 3 blocks/CU (LDS 48KB -> 3/CU; launch_bounds(256,3) caps
// VGPR so registers can't reduce capacity) => co-residency guaranteed.
// Exact tile counts: prep 5376=7*768, qkv 2304=3*768, attn 768, out 768.
// ---------------------------------------------------------------------------
__global__ __launch_bounds__(256, 3) void mega(
    const float* __restrict__ x, const float* __restrict__ w_qkv,
    const float* __restrict__ w_out, const float* __restrict__ b_out,
    uint16_t* __restrict__ xbf, uint16_t* __restrict__ qws,
    uint16_t* __restrict__ kws, uint16_t* __restrict__ vtws,
    uint16_t* __restrict__ attnws, uint16_t* __restrict__ wtqkv,
    uint16_t* __restrict__ wtout, float* __restrict__ outp,
    unsigned* bar) {
    __shared__ SMem sm;
    int bx = blockIdx.x, tid = threadIdx.x;

    // phase 1: prep (cvt x + transpose weights)
    for (int r = 0; r < 7; r++)
        prep_unit(r * 768 + bx, tid, x, xbf, w_qkv, wtqkv, w_out, wtout,
                  (uint16_t(*)[33])sm.tile);

    grid_barrier(bar + 0);

    // phase 2: QKV projection [8192,768]@[768,2304], 64x128 tiles x-major
    for (int r = 0; r < 3; r++) {
        int v = r * 768 + bx;
        gemm_tile<0>(v % 18, v / 18, xbf, wtqkv, 768, 2304, sm.g.lA, sm.g.lB,
                     qws, kws, vtws, nullptr, nullptr);
    }

    grid_barrier(bar + 1);

    // phase 3: attention (same-bh blocks land on one XCD: 96 % 8 == 0)
    attn_tile(bx % 96, bx / 96, qws, kws, vtws, attnws, sm.P);

    grid_barrier(bar + 2);

    // phase 4: out projection [8192,768]@[768,768]+bias, 64x128 tiles
    gemm_tile<1>(bx % 6, bx / 6, attnws, wtout, 768, 768, sm.g.lA, sm.g.lB,
                 nullptr, nullptr, nullptr, b_out, outp);
}

// ---------------------------------------------------------------------------
// Workspace layout (bytes), everything shifted +4096 for the barrier page:
//   bar    @ 0                 64 (memset each replay)
//   xbf    @ 4096       12,582,912
//   qws    @ 12586      +.. (see code)
// ---------------------------------------------------------------------------
extern "C" void kernel_launch(void* const* d_in, const int* in_sizes, int n_in,
                              void* d_out, int out_size, void* d_ws, size_t ws_size,
                              hipStream_t stream) {
    const float* x     = (const float*)d_in[0];
    const float* w_qkv = (const float*)d_in[1];
    const float* w_out = (const float*)d_in[2];
    const float* b_out = (const float*)d_in[3];
    float* out = (float*)d_out;

    char* ws = (char*)d_ws;
    const size_t OFF = 4096;
    unsigned* bar   = (unsigned*)ws;
    uint16_t* xbf   = (uint16_t*)(ws + OFF);
    uint16_t* qws   = (uint16_t*)(ws + OFF + 12582912);
    uint16_t* kws   = (uint16_t*)(ws + OFF + 25165824);
    uint16_t* vtws  = (uint16_t*)(ws + OFF + 37748736);
    uint16_t* attn  = (uint16_t*)(ws + OFF + 50331648);
    uint16_t* wtqkv = (uint16_t*)(ws + OFF + 62914560);
    uint16_t* wtout = (uint16_t*)(ws + OFF + 66453504);

    hipMemsetAsync(ws, 0, 64, stream);  // reset grid-barrier counters

    mega<<<768, 256, 0, stream>>>(x, w_qkv, w_out, b_out, xbf, qws, kws, vtws,
                                  attn, wtqkv, wtout, out, bar);
}

// Round 5
// 207.444 us; speedup vs baseline: 3.0311x; 3.0311x over previous
//
#include <hip/hip_runtime.h>
#include <stdint.h>

// ---------------------------------------------------------------------------
// MHSA: B=8, N=1024, C=768, H=12, HD=64, SCALE=0.125
// Inputs/outputs fp32; internal compute bf16 MFMA with fp32 accumulation.
// Round 16: REVERT to best-known config after two falsified experiments.
//  - Mega-kernel (R15): 3.5x uniform slowdown — VGPR allocator forced to 84
//    for an attn phase needing ~120 (spill/reload latency poisoning) + agent-
//    scope barrier fences (buffer_wbl2/inv) nuking per-XCD L2. REVERTED.
//  - XCD-chunked swizzle (R14): FETCH 72.6->45.7MB as designed but dur
//    63->73us — kernel not fetch-limited; correlated panel sweeps hot-spot
//    L2. REVERTED.
//  Kept: fused prep (R14, ~24us win from 2 fewer launch gaps), 64x128 BK=64
//  GEMM (R11 structure, 63us), barrier-free attn (R13, fragment-order
//  global K/V reads, L2-resident).
// ---------------------------------------------------------------------------

typedef __attribute__((ext_vector_type(8))) __bf16 bf16x8;
typedef __attribute__((ext_vector_type(4))) float f32x4;

__device__ __forceinline__ uint16_t f2bf(float f) {
    union { float f; unsigned u; } c; c.f = f;
    unsigned x = c.u;
    unsigned r = (x + 0x7FFFu + ((x >> 16) & 1u)) >> 16;  // round-nearest-even
    return (uint16_t)r;
}

__device__ __forceinline__ void gload_lds16(const uint16_t* g, uint16_t* l) {
    __builtin_amdgcn_global_load_lds(
        (const __attribute__((address_space(1))) unsigned int*)g,
        (__attribute__((address_space(3))) unsigned int*)l, 16, 0, 0);
}

// ---------------------------------------------------------------------------
// Fused prep: blocks [0,3072) convert x fp32->bf16 (8 elem/thread);
// blocks [3072,4800) transpose w_qkv [768][2304] -> bf16 [2304][768];
// blocks [4800,5376) transpose w_out [768][768] -> bf16 [768][768].
// ---------------------------------------------------------------------------
__global__ __launch_bounds__(256) void prep(
    const float* __restrict__ x, uint16_t* __restrict__ xbf,
    const float* __restrict__ w_qkv, uint16_t* __restrict__ wtqkv,
    const float* __restrict__ w_out, uint16_t* __restrict__ wtout) {
    __shared__ uint16_t tile[32][33];
    int bid = blockIdx.x;
    int tid = threadIdx.x;

    if (bid < 3072) {
        int i = (bid * 256 + tid) * 8;
        float4 a = *(const float4*)(x + i);
        float4 b = *(const float4*)(x + i + 4);
        union { uint16_t u[8]; uint4 v; } o;
        o.u[0] = f2bf(a.x); o.u[1] = f2bf(a.y); o.u[2] = f2bf(a.z); o.u[3] = f2bf(a.w);
        o.u[4] = f2bf(b.x); o.u[5] = f2bf(b.y); o.u[6] = f2bf(b.z); o.u[7] = f2bf(b.w);
        *(uint4*)(xbf + i) = o.v;
        return;
    }

    const float* src; uint16_t* dst; int Cc, bx, by;
    if (bid < 4800) {
        int id = bid - 3072;
        src = w_qkv; dst = wtqkv; Cc = 2304;
        bx = id % 72; by = id / 72;
    } else {
        int id = bid - 4800;
        src = w_out; dst = wtout; Cc = 768;
        bx = id % 24; by = id / 24;
    }
    const int R = 768;
    int tx = tid & 31, ty = tid >> 5;
    int c0 = bx * 32, r0 = by * 32;
#pragma unroll
    for (int i = 0; i < 4; i++) {
        int r = ty + i * 8;
        tile[r][tx] = f2bf(src[(size_t)(r0 + r) * Cc + c0 + tx]);
    }
    __syncthreads();
#pragma unroll
    for (int i = 0; i < 4; i++) {
        int r = ty + i * 8;
        dst[(size_t)(c0 + r) * R + r0 + tx] = tile[tx][r];
    }
}

// ---------------------------------------------------------------------------
// GEMM 64x128 block tile, BK=64 (two 32-k sub-tiles per barrier).
// XOR-swizzled staging (conflict-free frag reads), LDS double-buffer.
// MODE 0: QKV epilogue — q row-major pre-scaled by 0.125*log2e; k,v
//   scattered to per-32-key-tile fragment order. MODE 1: bias + fp32 out.
// ---------------------------------------------------------------------------
template <int MODE>
__global__ __launch_bounds__(256) void gemm128(
    const uint16_t* __restrict__ A, const uint16_t* __restrict__ Bt,
    int Kdim, int Ncols,
    uint16_t* __restrict__ qws, uint16_t* __restrict__ kws,
    uint16_t* __restrict__ vtws,
    const float* __restrict__ bias, float* __restrict__ outp) {
    __shared__ uint16_t lA[2][2][2048];   // [buf][sub][64 rows x 32 k]
    __shared__ uint16_t lB[2][2][4096];   // [buf][sub][128 rows x 32 k]

    int tid = threadIdx.x;
    int w = tid >> 6, lane = tid & 63, quad = lane >> 4, lo = lane & 15;
    int mw = w >> 1, nw = w & 1;
    int m0 = blockIdx.y * 64;
    int n0 = blockIdx.x * 128;

    // staging: thread t -> LDS row t>>2 col (t&3); global chunk XOR-swizzled
    int srow = tid >> 2;
    int skc = ((tid & 3) ^ ((tid >> 3) & 3)) * 8;
    const uint16_t* gA0 = A + (size_t)(m0 + srow) * Kdim + skc;
    const uint16_t* gB0 = Bt + (size_t)(n0 + srow) * Kdim + skc;
    const uint16_t* gB1 = gB0 + (size_t)64 * Kdim;

    f32x4 acc[2][4];
#pragma unroll
    for (int i = 0; i < 2; i++)
#pragma unroll
        for (int j = 0; j < 4; j++) acc[i][j] = (f32x4){0.f, 0.f, 0.f, 0.f};

    // reader base offsets (swizzled; i-invariant: 16/32-row steps preserve
    // (row>>1)&3 == (lo>>1)&3)
    int swz = (quad ^ ((lo >> 1) & 3)) * 8;
    int aoff = (mw * 32 + lo) * 32 + swz;
    int boff = (nw * 64 + lo) * 32 + swz;

    const int nIter = Kdim >> 6;  // BK=64

    // preload k-tile 0 (both sub-tiles) into buffer 0
#pragma unroll
    for (int s = 0; s < 2; s++) {
        gload_lds16(gA0 + s * 32, &lA[0][s][tid * 8]);
        gload_lds16(gB0 + s * 32, &lB[0][s][tid * 8]);
        gload_lds16(gB1 + s * 32, &lB[0][s][2048 + tid * 8]);
    }
    __syncthreads();

    for (int it = 0; it < nIter; it++) {
        const int cur = it & 1, nxt = cur ^ 1;
        const int kn = (it + 1 < nIter) ? (it + 1) * 64 : 0;  // last redundant

        // prefetch next 64-k tile (drained at the barrier, ~380 cyc later)
#pragma unroll
        for (int s = 0; s < 2; s++) {
            gload_lds16(gA0 + kn + s * 32, &lA[nxt][s][tid * 8]);
            gload_lds16(gB0 + kn + s * 32, &lB[nxt][s][tid * 8]);
            gload_lds16(gB1 + kn + s * 32, &lB[nxt][s][2048 + tid * 8]);
        }

#pragma unroll
        for (int s = 0; s < 2; s++) {
            bf16x8 af[2], bfr[4];
#pragma unroll
            for (int i = 0; i < 2; i++) af[i] = *(const bf16x8*)(&lA[cur][s][aoff + i * 512]);
#pragma unroll
            for (int j = 0; j < 4; j++) bfr[j] = *(const bf16x8*)(&lB[cur][s][boff + j * 512]);
#pragma unroll
            for (int i = 0; i < 2; i++)
#pragma unroll
                for (int j = 0; j < 4; j++)
                    acc[i][j] = __builtin_amdgcn_mfma_f32_16x16x32_bf16(
                        af[i], bfr[j], acc[i][j], 0, 0, 0);
        }
        __syncthreads();  // drains prefetch (hidden by 16 MFMAs) + WAR on cur
    }

    if (MODE == 0) {
        int part = n0 / 768;
        int ccb = n0 % 768 + nw * 64;
        float qsc = (part == 0) ? 0.18033688011112042f : 1.0f;  // 0.125*log2(e)
#pragma unroll
        for (int i = 0; i < 2; i++)
#pragma unroll
            for (int j = 0; j < 4; j++)
#pragma unroll
                for (int r = 0; r < 4; r++) {
                    int m = m0 + mw * 32 + i * 16 + quad * 4 + r;
                    int bidx = m >> 10, nidx = m & 1023;
                    int cc = ccb + j * 16 + lo;
                    int h = cc >> 6, d = cc & 63;
                    int bh = bidx * 12 + h;
                    uint16_t v = f2bf(acc[i][j][r] * qsc);
                    int kt = nidx >> 5, keyin = nidx & 31;
                    if (part == 0) {
                        qws[((size_t)bh * 1024 + nidx) * 64 + d] = v;
                    } else if (part == 1) {
                        int fs = ((d >> 5) << 1) | (keyin & 1);
                        int idx = ((bh << 5) + kt) * 2048 + fs * 512 +
                                  ((((d & 31) >> 3) << 4) + (keyin >> 1)) * 8 + (d & 7);
                        kws[idx] = v;
                    } else {
                        int idx = ((bh << 5) + kt) * 2048 + (d >> 4) * 512 +
                                  (((keyin >> 3) << 4) + (d & 15)) * 8 + (keyin & 7);
                        vtws[idx] = v;
                    }
                }
    } else {
#pragma unroll
        for (int i = 0; i < 2; i++)
#pragma unroll
            for (int j = 0; j < 4; j++)
#pragma unroll
                for (int r = 0; r < 4; r++) {
                    int m = m0 + mw * 32 + i * 16 + quad * 4 + r;
                    int c = n0 + nw * 64 + j * 16 + lo;
                    outp[(size_t)m * Ncols + c] = acc[i][j][r] + bias[c];
                }
    }
}

// ---------------------------------------------------------------------------
// Flash attention: NO K/V LDS staging. K/V read directly from global in
// fragment order (16 B/lane coalesced); per-XCD working set 12 bh x 256 KB
// = 3 MB < 4 MB L2 (grid is XCD-optimal: same-bh blocks differ by 96 = 0
// mod 8). Barrier-free; P staging is per-wave.
// grid (96 bh, 8 qt), block 256 = 4 waves x 32 q-rows.
// q pre-scaled (exp2 direct), perm-packed P, ones-MFMA row sums.
// ---------------------------------------------------------------------------
__global__ __launch_bounds__(256) void attn_kernel(
    const uint16_t* __restrict__ qws, const uint16_t* __restrict__ kws,
    const uint16_t* __restrict__ vtws, uint16_t* __restrict__ attnout) {
    int bh = blockIdx.x;
    int qt = blockIdx.y;
    int tid = threadIdx.x;
    int w = tid >> 6, lane = tid & 63, quad = lane >> 4, lo = lane & 15;
    int q0 = qt * 128 + w * 32;

    const uint16_t* Qb = qws + (size_t)bh * 65536;
    const uint16_t* Kt = kws + (size_t)bh * 65536;   // 32 tiles x 2048 u16
    const uint16_t* Vt = vtws + (size_t)bh * 65536;

    bf16x8 aq[2][2];
#pragma unroll
    for (int rg = 0; rg < 2; rg++)
#pragma unroll
        for (int h = 0; h < 2; h++)
            aq[rg][h] = *(const bf16x8*)(Qb + (size_t)(q0 + rg * 16 + lo) * 64 + h * 32 + quad * 8);

    f32x4 oacc[2][4], ol[2];
#pragma unroll
    for (int rg = 0; rg < 2; rg++) {
        ol[rg] = (f32x4){0.f, 0.f, 0.f, 0.f};
#pragma unroll
        for (int nd = 0; nd < 4; nd++) oacc[rg][nd] = (f32x4){0.f, 0.f, 0.f, 0.f};
    }

    bf16x8 ones;
#pragma unroll
    for (int i = 0; i < 8; i++) ones[i] = (__bf16)1.0f;

    __shared__ uint16_t P[4][2][16][40];     // per-wave C->A staging (10 KB)

    const f32x4 zero4 = (f32x4){0.f, 0.f, 0.f, 0.f};

#pragma unroll 2
    for (int kt = 0; kt < 32; kt++) {
        const uint16_t* Kb = Kt + kt * 2048;
        const uint16_t* Vb = Vt + kt * 2048;

        // direct global fragment loads (each 16 B/lane, 1 KB/wave coalesced;
        // L2-resident after first touch)
        bf16x8 bk[2][2], vv[4];
#pragma unroll
        for (int t = 0; t < 2; t++)
#pragma unroll
            for (int h = 0; h < 2; h++)
                bk[t][h] = *(const bf16x8*)(Kb + (h * 2 + t) * 512 + lane * 8);
#pragma unroll
        for (int nd = 0; nd < 4; nd++)
            vv[nd] = *(const bf16x8*)(Vb + nd * 512 + lane * 8);

#pragma unroll
        for (int rg = 0; rg < 2; rg++) {
            f32x4 s0 = __builtin_amdgcn_mfma_f32_16x16x32_bf16(aq[rg][0], bk[0][0], zero4, 0, 0, 0);
            s0 = __builtin_amdgcn_mfma_f32_16x16x32_bf16(aq[rg][1], bk[0][1], s0, 0, 0, 0);
            f32x4 s1 = __builtin_amdgcn_mfma_f32_16x16x32_bf16(aq[rg][0], bk[1][0], zero4, 0, 0, 0);
            s1 = __builtin_amdgcn_mfma_f32_16x16x32_bf16(aq[rg][1], bk[1][1], s1, 0, 0, 0);
#pragma unroll
            for (int r = 0; r < 4; r++) {
                union { float f; unsigned u; } u0, u1;
                u0.f = __builtin_exp2f(s0[r]);  // key 2*lo
                u1.f = __builtin_exp2f(s1[r]);  // key 2*lo+1
                unsigned pk = __builtin_amdgcn_perm(u1.u, u0.u, 0x07060302u);
                *(unsigned*)&P[w][rg][quad * 4 + r][2 * lo] = pk;
            }
        }

#pragma unroll
        for (int rg = 0; rg < 2; rg++) {
            bf16x8 ap = *(const bf16x8*)(&P[w][rg][lo][quad * 8]);
            ol[rg] = __builtin_amdgcn_mfma_f32_16x16x32_bf16(ap, ones, ol[rg], 0, 0, 0);
#pragma unroll
            for (int nd = 0; nd < 4; nd++)
                oacc[rg][nd] = __builtin_amdgcn_mfma_f32_16x16x32_bf16(ap, vv[nd], oacc[rg][nd], 0, 0, 0);
        }
    }

    int b = bh / 12, hh = bh % 12;
#pragma unroll
    for (int rg = 0; rg < 2; rg++)
#pragma unroll
        for (int r = 0; r < 4; r++) {
            float inv = 1.0f / ol[rg][r];
            int n = q0 + rg * 16 + quad * 4 + r;
            size_t base = ((size_t)(b * 1024 + n)) * 768 + hh * 64;
#pragma unroll
            for (int nd = 0; nd < 4; nd++)
                attnout[base + nd * 16 + lo] = f2bf(oacc[rg][nd][r] * inv);
        }
}

// ---------------------------------------------------------------------------
// Workspace layout (bytes):
//   xbf    @ 0          12,582,912
//   qws    @ 12582912   12,582,912
//   kws    @ 25165824   12,582,912   (tile-fragment order)
//   vtws   @ 37748736   12,582,912   (tile-fragment order)
//   attn   @ 50331648   12,582,912
//   wtqkv  @ 62914560    3,538,944
//   wtout  @ 66453504    1,179,648
// ---------------------------------------------------------------------------
extern "C" void kernel_launch(void* const* d_in, const int* in_sizes, int n_in,
                              void* d_out, int out_size, void* d_ws, size_t ws_size,
                              hipStream_t stream) {
    const float* x     = (const float*)d_in[0];
    const float* w_qkv = (const float*)d_in[1];
    const float* w_out = (const float*)d_in[2];
    const float* b_out = (const float*)d_in[3];
    float* out = (float*)d_out;

    char* ws = (char*)d_ws;
    uint16_t* xbf   = (uint16_t*)(ws);
    uint16_t* qws   = (uint16_t*)(ws + 12582912);
    uint16_t* kws   = (uint16_t*)(ws + 25165824);
    uint16_t* vtws  = (uint16_t*)(ws + 37748736);
    uint16_t* attn  = (uint16_t*)(ws + 50331648);
    uint16_t* wtqkv = (uint16_t*)(ws + 62914560);
    uint16_t* wtout = (uint16_t*)(ws + 66453504);

    // fused prep: cvt (3072 blocks) + w_qkv transpose (1728) + w_out (576)
    prep<<<5376, 256, 0, stream>>>(x, xbf, w_qkv, wtqkv, w_out, wtout);

    // QKV projection: [8192,768] @ [768,2304], 64x128 tiles (2304 blocks)
    gemm128<0><<<dim3(18, 128), 256, 0, stream>>>(
        xbf, wtqkv, 768, 2304, qws, kws, vtws, nullptr, nullptr);

    attn_kernel<<<dim3(96, 8), 256, 0, stream>>>(qws, kws, vtws, attn);

    // out projection: [8192,768] @ [768,768] + bias, 64x128 tiles (768 blocks)
    gemm128<1><<<dim3(6, 128), 256, 0, stream>>>(
        attn, wtout, 768, 768, nullptr, nullptr, nullptr, b_out, out);
}